// Round 6
// baseline (188.428 us; speedup 1.0000x reference)
//
#include <hip/hip_runtime.h>
#include <math.h>

// Fixed problem dims from setup_inputs()
#define BATCH 2
#define C 64
#define HIN 128
#define WIN 128
#define HW (HIN * WIN)
#define OH 256
#define OW 256
#define SCALE 2.0f

#define BLK 256
#define PIX 64   // pixels per block (64 consecutive ox within one oy row)
#define SC 16    // channels per thread-slice (4 slices)
#define TCOLS 40 // tile cols (aligned float4 window, covers the 37 needed)

// Round-6: round-5 wave-cooperative structure + cooperative LDS x-tile for
// sampling-1. A block's 64 pixels share one oy row -> sampling-1 needs just
// 2 input rows x <=37 cols per channel (block-uniform window). Coop-loading
// that tile costs 5 float4 wave-instrs vs 64 divergent gathers (round-5's
// suspected TA/latency bottleneck; 128 gathers/wave, VALUBusy 41%).
// One 20 KB LDS region is reused barrier-separated:
//   x-tile (20K) -> pf (16K) -> h1 (16K) -> head partials (6K) -> comp (8K).
// 20 KB -> 8 blocks/CU; launch_bounds(256,8) forces VGPR<=64 so all 8 fit.

__global__ __launch_bounds__(BLK, 8) void scab_kernel(
    const float* __restrict__ x,    // (B, C, HIN, WIN)
    const float* __restrict__ wcm,  // weight_compress (4, 8, 64)
    const float* __restrict__ wex,  // weight_expand   (4, 64, 8)
    const float* __restrict__ w1,   // (64, 68)
    const float* __restrict__ b1,   // (64)
    const float* __restrict__ w2,   // (64, 64)
    const float* __restrict__ b2,   // (64)
    const float* __restrict__ wr,   // (4, 64)
    const float* __restrict__ br,   // (4)
    const float* __restrict__ wo,   // (2, 64)
    const float* __restrict__ bo,   // (2)
    float* __restrict__ out)        // (B, C, OH, OW)
{
    __shared__ __align__(16) float sbuf[C * 2 * TCOLS];   // 20 KB, overlaid phases

    const int tid = threadIdx.x;
    const int p   = tid & 63;                                   // pixel within block
    const int s   = __builtin_amdgcn_readfirstlane(tid >> 6);   // slice == wave id
    const int cb  = s * SC;                                     // my channel base

    const int gp = blockIdx.x * PIX + p;
    const int ox = gp & (OW - 1);
    const int oy = (gp >> 8) & (OH - 1);
    const int bb = gp >> 16;

    // ---- coords channels (match reference exactly) ----
    const float c01 = 1.0f / SCALE;
    const float fhh = (oy + 0.5f) / SCALE;
    const float coor_h = fhh - floorf(fhh + 0.001f) - 0.5f;
    const float fww = (ox + 0.5f) / SCALE;
    const float coor_w = fww - floorf(fww + 0.001f) - 0.5f;

    // ---- base grid ----
    const float gx = ((ox + 0.5f) / SCALE - 0.5f) * (2.0f / (WIN - 1)) - 1.0f;
    const float gy = ((oy + 0.5f) / SCALE - 0.5f) * (2.0f / (HIN - 1)) - 1.0f;

    const float* __restrict__ xb = x + bb * (C * HW);

    // ---- sampling-1 geometry (y is block-uniform; x window block-uniform) ----
    // rows
    const float fy = ((gy + 1.0f) * HIN - 1.0f) * 0.5f;
    const float y0f = floorf(fy);
    const float wy1 = fy - y0f, wy0 = 1.0f - wy1;
    const bool vy0 = (y0f >= 0.0f) && (y0f <= (float)(HIN - 1));
    const bool vy1 = (y0f + 1.0f >= 0.0f) && (y0f + 1.0f <= (float)(HIN - 1));
    const int yi0 = (int)fminf(fmaxf(y0f, 0.0f), (float)(HIN - 1));
    const int yi1 = (int)fminf(fmaxf(y0f + 1.0f, 0.0f), (float)(HIN - 1));
    // cols
    const float fx = ((gx + 1.0f) * WIN - 1.0f) * 0.5f;
    const float x0f = floorf(fx);
    const float wx1 = fx - x0f, wx0 = 1.0f - wx1;
    const bool vx0 = (x0f >= 0.0f) && (x0f <= (float)(WIN - 1));
    const bool vx1 = (x0f + 1.0f >= 0.0f) && (x0f + 1.0f <= (float)(WIN - 1));
    const int xi0 = (int)fminf(fmaxf(x0f, 0.0f), (float)(WIN - 1));
    const int xi1 = (int)fminf(fmaxf(x0f + 1.0f, 0.0f), (float)(WIN - 1));
    const float w00 = wx0 * wy0 * ((vx0 && vy0) ? 1.0f : 0.0f);
    const float w10 = wx1 * wy0 * ((vx1 && vy0) ? 1.0f : 0.0f);
    const float w01 = wx0 * wy1 * ((vx0 && vy1) ? 1.0f : 0.0f);
    const float w11 = wx1 * wy1 * ((vx1 && vy1) ? 1.0f : 0.0f);

    // block-uniform aligned col-window start: tile[c][r][j] = x[c][row_r][cxa+j]
    const int ox_base = (blockIdx.x * PIX) & (OW - 1);
    int cxa = ((ox_base >> 1) - 1) & ~3;
    cxa = min(max(cxa, 0), WIN - TCOLS);          // window always fully in-bounds

    // ===== phase 1: cooperative x-tile load (1280 float4 chunks, 5/thread) =====
    {
        #pragma unroll
        for (int i = 0; i < 5; ++i) {
            const int q   = tid + BLK * i;        // 0..1279
            const int c   = q / 20;               // 20 chunks per channel
            const int rem = q - c * 20;
            const int r   = rem / 10;
            const int jb  = rem - r * 10;
            const int row = r ? yi1 : yi0;
            const float4 v = *(const float4*)(xb + c * HW + row * WIN + cxa + jb * 4);
            *(float4*)(&sbuf[(c * 2 + r) * TCOLS + jb * 4]) = v;
        }
    }
    __syncthreads();

    // ===== phase 2: pf for my 16 channels, from tile, into registers =====
    const int j0  = xi0 - cxa;                    // in [0, TCOLS-1]
    const int jj1 = xi1 - cxa;
    float pf[SC];
    #pragma unroll
    for (int k = 0; k < SC; ++k) {
        const float* __restrict__ t = &sbuf[((cb + k) * 2) * TCOLS];
        const float t00 = t[j0], t10 = t[jj1];
        const float t01 = t[TCOLS + j0], t11 = t[TCOLS + jj1];
        pf[k] = t00 * w00 + t10 * w10 + t01 * w01 + t11 * w11;
    }
    __syncthreads();                              // tile reads done

    // ===== phase 3: pf -> LDS [c*64+p] =====
    #pragma unroll
    for (int k = 0; k < SC; ++k) sbuf[(cb + k) * PIX + p] = pf[k];
    __syncthreads();

    // ===== phase 4: conv1 (68 -> my 16), accumulator form over pf in LDS =====
    float h[SC];
    #pragma unroll
    for (int k = 0; k < SC; ++k) {
        const float* __restrict__ wrow = w1 + (cb + k) * (C + 4);
        h[k] = fmaf(wrow[3], coor_w, fmaf(wrow[2], coor_h,
               fmaf(wrow[1], c01,    fmaf(wrow[0], c01, b1[cb + k]))));
    }
    for (int c = 0; c < C; c += 4) {
        const float p0 = sbuf[(c + 0) * PIX + p];
        const float p1 = sbuf[(c + 1) * PIX + p];
        const float p2 = sbuf[(c + 2) * PIX + p];
        const float p3 = sbuf[(c + 3) * PIX + p];
        #pragma unroll
        for (int k = 0; k < SC; ++k) {
            const float* __restrict__ wrow = w1 + (cb + k) * (C + 4) + 4 + c;
            h[k] = fmaf(wrow[0], p0, fmaf(wrow[1], p1,
                   fmaf(wrow[2], p2, fmaf(wrow[3], p3, h[k]))));
        }
    }
    #pragma unroll
    for (int k = 0; k < SC; ++k) h[k] = fmaxf(h[k], 0.0f);
    __syncthreads();                              // pf reads done

    // ===== phase 5: h1 -> LDS =====
    #pragma unroll
    for (int k = 0; k < SC; ++k) sbuf[(cb + k) * PIX + p] = h[k];
    __syncthreads();

    // ===== phase 6: conv2 (64 -> my 16) + head partials =====
    float a[SC];
    #pragma unroll
    for (int k = 0; k < SC; ++k) a[k] = b2[cb + k];
    for (int c = 0; c < C; c += 4) {
        const float h0 = sbuf[(c + 0) * PIX + p];
        const float h1v = sbuf[(c + 1) * PIX + p];
        const float h2v = sbuf[(c + 2) * PIX + p];
        const float h3v = sbuf[(c + 3) * PIX + p];
        #pragma unroll
        for (int k = 0; k < SC; ++k) {
            const float* __restrict__ wrow = w2 + (cb + k) * C + c;
            a[k] = fmaf(wrow[0], h0, fmaf(wrow[1], h1v,
                   fmaf(wrow[2], h2v, fmaf(wrow[3], h3v, a[k]))));
        }
    }
    float hx = 0.0f, hy = 0.0f, z0p = 0.0f, z1p = 0.0f, z2p = 0.0f, z3p = 0.0f;
    #pragma unroll
    for (int k = 0; k < SC; ++k) {
        const float e = fmaxf(a[k], 0.0f);
        const int o = cb + k;
        hx  = fmaf(wo[o],         e, hx);
        hy  = fmaf(wo[C + o],     e, hy);
        z0p = fmaf(wr[o],         e, z0p);
        z1p = fmaf(wr[C + o],     e, z1p);
        z2p = fmaf(wr[2 * C + o], e, z2p);
        z3p = fmaf(wr[3 * C + o], e, z3p);
    }
    __syncthreads();                              // h1 reads done

    // ===== phase 7: head partials -> LDS, cross-slice reduce =====
    sbuf[0 * 256 + s * 64 + p] = hx;
    sbuf[1 * 256 + s * 64 + p] = hy;
    sbuf[2 * 256 + s * 64 + p] = z0p;
    sbuf[3 * 256 + s * 64 + p] = z1p;
    sbuf[4 * 256 + s * 64 + p] = z2p;
    sbuf[5 * 256 + s * 64 + p] = z3p;
    __syncthreads();

    float offx = bo[0], offy = bo[1];
    float z0 = br[0], z1 = br[1], z2 = br[2], z3 = br[3];
    #pragma unroll
    for (int ss = 0; ss < 4; ++ss) {              // fixed order: identical in all slices
        offx += sbuf[0 * 256 + ss * 64 + p];
        offy += sbuf[1 * 256 + ss * 64 + p];
        z0   += sbuf[2 * 256 + ss * 64 + p];
        z1   += sbuf[3 * 256 + ss * 64 + p];
        z2   += sbuf[4 * 256 + ss * 64 + p];
        z3   += sbuf[5 * 256 + ss * 64 + p];
    }
    const float rg0 = 1.0f / (1.0f + __expf(-z0));
    const float rg1 = 1.0f / (1.0f + __expf(-z1));
    const float rg2 = 1.0f / (1.0f + __expf(-z2));
    const float rg3 = 1.0f / (1.0f + __expf(-z3));

    // ===== phase 8: sampling-2 (per-pixel offsets, global gathers) + compress =====
    float f[SC];
    float cp[8];
    #pragma unroll
    for (int d = 0; d < 8; ++d) cp[d] = 0.0f;
    {
        const float ix2 = gx + offx * (2.0f / (WIN - 1));
        const float iy2 = gy + offy * (2.0f / (HIN - 1));
        const float fx2 = ((ix2 + 1.0f) * WIN - 1.0f) * 0.5f;
        const float fy2 = ((iy2 + 1.0f) * HIN - 1.0f) * 0.5f;
        const float x0s = floorf(fx2), y0s = floorf(fy2);
        const float sx1 = fx2 - x0s, sx0 = 1.0f - sx1;
        const float sy1 = fy2 - y0s, sy0 = 1.0f - sy1;
        const bool ux0 = (x0s >= 0.0f) && (x0s <= (float)(WIN - 1));
        const bool ux1 = (x0s + 1.0f >= 0.0f) && (x0s + 1.0f <= (float)(WIN - 1));
        const bool uy0 = (y0s >= 0.0f) && (y0s <= (float)(HIN - 1));
        const bool uy1 = (y0s + 1.0f >= 0.0f) && (y0s + 1.0f <= (float)(HIN - 1));
        const int sxi0 = (int)fminf(fmaxf(x0s, 0.0f), (float)(WIN - 1));
        const int sxi1 = (int)fminf(fmaxf(x0s + 1.0f, 0.0f), (float)(WIN - 1));
        const int syi0 = (int)fminf(fmaxf(y0s, 0.0f), (float)(HIN - 1));
        const int syi1 = (int)fminf(fmaxf(y0s + 1.0f, 0.0f), (float)(HIN - 1));
        const float v00 = sx0 * sy0 * ((ux0 && uy0) ? 1.0f : 0.0f);
        const float v10 = sx1 * sy0 * ((ux1 && uy0) ? 1.0f : 0.0f);
        const float v01 = sx0 * sy1 * ((ux0 && uy1) ? 1.0f : 0.0f);
        const float v11 = sx1 * sy1 * ((ux1 && uy1) ? 1.0f : 0.0f);
        const int jg00 = syi0 * WIN + sxi0;
        const int jg10 = syi0 * WIN + sxi1;
        const int jg01 = syi1 * WIN + sxi0;
        const int jg11 = syi1 * WIN + sxi1;
        #pragma unroll
        for (int kk = 0; kk < SC; kk += 4) {
            float l[16];
            #pragma unroll
            for (int k = 0; k < 4; ++k) {
                const float* __restrict__ xc = xb + (cb + kk + k) * HW;
                l[4*k+0] = xc[jg00]; l[4*k+1] = xc[jg10];
                l[4*k+2] = xc[jg01]; l[4*k+3] = xc[jg11];
            }
            #pragma unroll
            for (int k = 0; k < 4; ++k) {
                const float fc = l[4*k]*v00 + l[4*k+1]*v10 + l[4*k+2]*v01 + l[4*k+3]*v11;
                f[kk + k] = fc;
                const int c = cb + kk + k;
                const float s0 = rg0 * fc, s1 = rg1 * fc, s2 = rg2 * fc, s3 = rg3 * fc;
                #pragma unroll
                for (int d = 0; d < 8; ++d) {
                    cp[d] = fmaf(wcm[(0 * 8 + d) * C + c], s0, cp[d]);
                    cp[d] = fmaf(wcm[(1 * 8 + d) * C + c], s1, cp[d]);
                    cp[d] = fmaf(wcm[(2 * 8 + d) * C + c], s2, cp[d]);
                    cp[d] = fmaf(wcm[(3 * 8 + d) * C + c], s3, cp[d]);
                }
            }
        }
    }
    __syncthreads();                              // head-partial reads done

    // ===== phase 9: comp partials -> LDS, cross-slice reduce =====
    #pragma unroll
    for (int d = 0; d < 8; ++d) sbuf[d * 256 + s * 64 + p] = cp[d];
    __syncthreads();

    float comp[8];
    #pragma unroll
    for (int d = 0; d < 8; ++d) {
        float v = sbuf[d * 256 + 0 * 64 + p];
        v += sbuf[d * 256 + 1 * 64 + p];
        v += sbuf[d * 256 + 2 * 64 + p];
        v += sbuf[d * 256 + 3 * 64 + p];
        comp[d] = v;
    }

    // ===== phase 10: expand + residual for my 16 channels =====
    float* __restrict__ ob = out + bb * (C * OH * OW) + oy * OW + ox;
    #pragma unroll
    for (int k = 0; k < SC; ++k) {
        const int c = cb + k;
        const float* __restrict__ we0 = wex + (0 * C + c) * 8;
        const float* __restrict__ we1 = wex + (1 * C + c) * 8;
        const float* __restrict__ we2 = wex + (2 * C + c) * 8;
        const float* __restrict__ we3 = wex + (3 * C + c) * 8;
        float s0 = 0.0f, s1 = 0.0f, s2 = 0.0f, s3 = 0.0f;
        #pragma unroll
        for (int d = 0; d < 8; ++d) {
            s0 = fmaf(we0[d], comp[d], s0);
            s1 = fmaf(we1[d], comp[d], s1);
            s2 = fmaf(we2[d], comp[d], s2);
            s3 = fmaf(we3[d], comp[d], s3);
        }
        float acc = f[k];
        acc = fmaf(rg0, s0, acc);
        acc = fmaf(rg1, s1, acc);
        acc = fmaf(rg2, s2, acc);
        acc = fmaf(rg3, s3, acc);
        ob[c * (OH * OW)] = acc;                  // coalesced over 64 consecutive ox
    }
}

extern "C" void kernel_launch(void* const* d_in, const int* in_sizes, int n_in,
                              void* d_out, int out_size, void* d_ws, size_t ws_size,
                              hipStream_t stream) {
    const float* x   = (const float*)d_in[0];
    const float* wcm = (const float*)d_in[1];
    const float* wex = (const float*)d_in[2];
    const float* w1  = (const float*)d_in[3];
    const float* b1  = (const float*)d_in[4];
    const float* w2  = (const float*)d_in[5];
    const float* b2  = (const float*)d_in[6];
    const float* wr  = (const float*)d_in[7];
    const float* br  = (const float*)d_in[8];
    const float* wo  = (const float*)d_in[9];
    const float* bo  = (const float*)d_in[10];
    float* out = (float*)d_out;

    const int total  = BATCH * OH * OW;    // 131072 pixels
    const int blocks = total / PIX;        // 2048 blocks of 256 threads
    scab_kernel<<<blocks, BLK, 0, stream>>>(x, wcm, wex, w1, b1, w2, b2,
                                            wr, br, wo, bo, out);
}

// Round 7
// 124.870 us; speedup vs baseline: 1.5090x; 1.5090x over previous
//
#include <hip/hip_runtime.h>
#include <math.h>

// Fixed problem dims from setup_inputs()
#define BATCH 2
#define C 64
#define HIN 128
#define WIN 128
#define HW (HIN * WIN)
#define OH 256
#define OW 256

#define BLK 256
#define PIX 64    // pixels per block (64 consecutive ox in one oy row)
#define SC 16     // channels per thread-slice (4 slices)
#define ASTR 72   // act row stride in shorts: 16B-aligned rows, breaks the
                  // stride-64 16-way LDS bank conflict (72*2=144B = 9 lines)

// Round-7: convs on matrix cores. Round-6 evidence: VALU-issue ~55us is the
// limiter (occupancy 63% bought nothing), and conv1+conv2 are 2/3 of VALU.
// Per block both convs are [64pix x 64] x [64 x 64] GEMMs:
//  - mfma_f32_16x16x32_bf16, verified layouts: A[m=lane&15][k=quad*8+j],
//    B[n=lane&15][k=quad*8+j], D col=lane&15(n), row=quad*4+reg(m).
//  - B-frags (weights) load straight from global (rows are k-contiguous),
//    held in 8 VGPRs per K-step. No weight LDS.
//  - coords channels folded into MFMA C-init: for scale=2,
//    coor_h/w = +-0.25 by oy/ox parity; ones=0.5. q[n]=b1+...
//  - activations: one bf16 LDS buffer act[64][72], overlaid pf->h1->emb.
// Sampling / heads / compress / expand stay fp32 (residual path precision).

typedef __attribute__((ext_vector_type(8))) short bf16x8;
typedef __attribute__((ext_vector_type(4))) float f32x4;

__device__ __forceinline__ unsigned short f2bf(float f) {
    unsigned u = __float_as_uint(f);
    u += 0x7FFFu + ((u >> 16) & 1u);          // round-to-nearest-even
    return (unsigned short)(u >> 16);
}
__device__ __forceinline__ float bf2f(unsigned short s) {
    return __uint_as_float(((unsigned)s) << 16);
}

__device__ __forceinline__ void bilin_setup(float gx, float gy,
    int& i00, int& i10, int& i01, int& i11,
    float& w00, float& w10, float& w01, float& w11)
{
    const float fx = ((gx + 1.0f) * WIN - 1.0f) * 0.5f;
    const float fy = ((gy + 1.0f) * HIN - 1.0f) * 0.5f;
    const float x0 = floorf(fx), y0 = floorf(fy);
    const float wx1 = fx - x0, wx0 = 1.0f - wx1;
    const float wy1 = fy - y0, wy0 = 1.0f - wy1;
    const float x1 = x0 + 1.0f, y1 = y0 + 1.0f;
    const bool vx0 = (x0 >= 0.0f) && (x0 <= (float)(WIN - 1));
    const bool vx1 = (x1 >= 0.0f) && (x1 <= (float)(WIN - 1));
    const bool vy0 = (y0 >= 0.0f) && (y0 <= (float)(HIN - 1));
    const bool vy1 = (y1 >= 0.0f) && (y1 <= (float)(HIN - 1));
    const int xi0 = (int)fminf(fmaxf(x0, 0.0f), (float)(WIN - 1));
    const int xi1 = (int)fminf(fmaxf(x1, 0.0f), (float)(WIN - 1));
    const int yi0 = (int)fminf(fmaxf(y0, 0.0f), (float)(HIN - 1));
    const int yi1 = (int)fminf(fmaxf(y1, 0.0f), (float)(HIN - 1));
    w00 = wx0 * wy0 * ((vx0 && vy0) ? 1.0f : 0.0f);
    w10 = wx1 * wy0 * ((vx1 && vy0) ? 1.0f : 0.0f);
    w01 = wx0 * wy1 * ((vx0 && vy1) ? 1.0f : 0.0f);
    w11 = wx1 * wy1 * ((vx1 && vy1) ? 1.0f : 0.0f);
    i00 = yi0 * WIN + xi0;  i10 = yi0 * WIN + xi1;
    i01 = yi1 * WIN + xi0;  i11 = yi1 * WIN + xi1;
}

__global__ __launch_bounds__(BLK, 4) void scab_kernel(
    const float* __restrict__ x,    // (B, C, HIN, WIN)
    const float* __restrict__ wcm,  // weight_compress (4, 8, 64)
    const float* __restrict__ wex,  // weight_expand   (4, 64, 8)
    const float* __restrict__ w1,   // (64, 68)
    const float* __restrict__ b1,   // (64)
    const float* __restrict__ w2,   // (64, 64)
    const float* __restrict__ b2,   // (64)
    const float* __restrict__ wr,   // (4, 64)
    const float* __restrict__ br,   // (4)
    const float* __restrict__ wo,   // (2, 64)
    const float* __restrict__ bo,   // (2)
    float* __restrict__ out)        // (B, C, OH, OW)
{
    __shared__ __align__(16) short act[PIX * ASTR];   // 9216 B: pf -> h1 -> emb
    __shared__ float red[8 * BLK];                    // 8192 B: head/comp partials

    const int tid  = threadIdx.x;
    const int lane = tid & 63;                                  // pixel within block
    const int s    = __builtin_amdgcn_readfirstlane(tid >> 6);  // slice == wave id
    const int cb   = s * SC;
    const int l15  = lane & 15;
    const int quad = lane >> 4;
    const int nn   = cb + l15;                                  // my MFMA out-ch col

    const int gp = blockIdx.x * PIX + lane;
    const int ox = gp & (OW - 1);
    const int oy = (gp >> 8) & (OH - 1);
    const int bb = gp >> 16;

    // ---- base grid (fp32, matches reference) ----
    const float gx = ((ox + 0.5f) * 0.5f - 0.5f) * (2.0f / (WIN - 1)) - 1.0f;
    const float gy = ((oy + 0.5f) * 0.5f - 0.5f) * (2.0f / (HIN - 1)) - 1.0f;

    const float* __restrict__ xb = x + bb * (C * HW);

    // ===== B-frags: w1/w2 rows are [n][k] k-contiguous -> straight to VGPRs =====
    bf16x8 bw1[2], bw2[2];
    #pragma unroll
    for (int ks = 0; ks < 2; ++ks) {
        const float* __restrict__ s1p = w1 + nn * (C + 4) + 4 + ks * 32 + quad * 8;
        const float* __restrict__ s2p = w2 + nn * C + ks * 32 + quad * 8;
        #pragma unroll
        for (int j = 0; j < 8; ++j) {
            bw1[ks][j] = (short)f2bf(s1p[j]);
            bw2[ks][j] = (short)f2bf(s2p[j]);
        }
    }

    // ===== phase 1: sampling-1 gathers (my 16 ch), pf -> bf16 LDS act[pix][ch] =====
    {
        int i00, i10, i01, i11;
        float w00, w10, w01, w11;
        bilin_setup(gx, gy, i00, i10, i01, i11, w00, w10, w01, w11);
        bf16x8 v0, v1;
        #pragma unroll
        for (int kk = 0; kk < SC; kk += 4) {
            float l[16];
            #pragma unroll
            for (int k = 0; k < 4; ++k) {
                const float* __restrict__ xc = xb + (cb + kk + k) * HW;
                l[4*k+0] = xc[i00]; l[4*k+1] = xc[i10];
                l[4*k+2] = xc[i01]; l[4*k+3] = xc[i11];
            }
            #pragma unroll
            for (int k = 0; k < 4; ++k) {
                const float pf = l[4*k]*w00 + l[4*k+1]*w10 + l[4*k+2]*w01 + l[4*k+3]*w11;
                const short b = (short)f2bf(pf);
                if (kk + k < 8) v0[kk + k] = b; else v1[kk + k - 8] = b;
            }
        }
        *(bf16x8*)&act[lane * ASTR + cb]     = v0;
        *(bf16x8*)&act[lane * ASTR + cb + 8] = v1;
    }
    __syncthreads();

    // ===== phase 2: conv1 via MFMA; coords+bias folded into C-init =====
    // coor_h/w = +-0.25 by parity (scale=2); ox_base is 64-aligned -> even,
    // so pixel-row parity == reg parity inside the D-fragment.
    const float coor_h = (oy & 1) ? 0.25f : -0.25f;
    f32x4 acc[4];
    {
        const float4 wh = *(const float4*)(w1 + nn * (C + 4));   // w1[n][0..3]
        const float qn = b1[nn] + (wh.x + wh.y) * 0.5f + wh.z * coor_h;
        const float e0 = qn - 0.25f * wh.w;    // even pixel rows (reg 0,2)
        const float e1 = qn + 0.25f * wh.w;    // odd  pixel rows (reg 1,3)
        #pragma unroll
        for (int t = 0; t < 4; ++t) acc[t] = (f32x4){e0, e1, e0, e1};
    }
    #pragma unroll
    for (int t = 0; t < 4; ++t) {
        #pragma unroll
        for (int ks = 0; ks < 2; ++ks) {
            const bf16x8 af = *(const bf16x8*)&act[(t*16 + l15) * ASTR + ks*32 + quad*8];
            acc[t] = __builtin_amdgcn_mfma_f32_16x16x32_bf16(af, bw1[ks], acc[t], 0, 0, 0);
        }
    }
    __syncthreads();                            // all pf reads done
    #pragma unroll
    for (int t = 0; t < 4; ++t)
        #pragma unroll
        for (int r = 0; r < 4; ++r)
            act[(t*16 + quad*4 + r) * ASTR + nn] = (short)f2bf(fmaxf(acc[t][r], 0.0f));
    __syncthreads();

    // ===== phase 3: conv2 via MFMA =====
    {
        const float b2n = b2[nn];
        #pragma unroll
        for (int t = 0; t < 4; ++t) acc[t] = (f32x4){b2n, b2n, b2n, b2n};
    }
    #pragma unroll
    for (int t = 0; t < 4; ++t) {
        #pragma unroll
        for (int ks = 0; ks < 2; ++ks) {
            const bf16x8 af = *(const bf16x8*)&act[(t*16 + l15) * ASTR + ks*32 + quad*8];
            acc[t] = __builtin_amdgcn_mfma_f32_16x16x32_bf16(af, bw2[ks], acc[t], 0, 0, 0);
        }
    }
    __syncthreads();                            // all h1 reads done
    #pragma unroll
    for (int t = 0; t < 4; ++t)
        #pragma unroll
        for (int r = 0; r < 4; ++r)
            act[(t*16 + quad*4 + r) * ASTR + nn] = (short)f2bf(fmaxf(acc[t][r], 0.0f));
    __syncthreads();

    // ===== phase 4: heads (per-thread, pixel=lane, my 16 emb channels) =====
    float hx = 0.0f, hy = 0.0f, z0p = 0.0f, z1p = 0.0f, z2p = 0.0f, z3p = 0.0f;
    {
        const bf16x8 u0 = *(const bf16x8*)&act[lane * ASTR + cb];
        const bf16x8 u1 = *(const bf16x8*)&act[lane * ASTR + cb + 8];
        float em[SC];
        #pragma unroll
        for (int k = 0; k < 8; ++k) {
            em[k]     = bf2f((unsigned short)u0[k]);
            em[8 + k] = bf2f((unsigned short)u1[k]);
        }
        #pragma unroll
        for (int k = 0; k < SC; ++k) {
            const int o = cb + k;
            const float e = em[k];
            hx  = fmaf(wo[o],         e, hx);
            hy  = fmaf(wo[C + o],     e, hy);
            z0p = fmaf(wr[o],         e, z0p);
            z1p = fmaf(wr[C + o],     e, z1p);
            z2p = fmaf(wr[2 * C + o], e, z2p);
            z3p = fmaf(wr[3 * C + o], e, z3p);
        }
    }
    red[0 * 256 + s * 64 + lane] = hx;
    red[1 * 256 + s * 64 + lane] = hy;
    red[2 * 256 + s * 64 + lane] = z0p;
    red[3 * 256 + s * 64 + lane] = z1p;
    red[4 * 256 + s * 64 + lane] = z2p;
    red[5 * 256 + s * 64 + lane] = z3p;
    __syncthreads();

    float offx = bo[0], offy = bo[1];
    float z0 = br[0], z1 = br[1], z2 = br[2], z3 = br[3];
    #pragma unroll
    for (int ss = 0; ss < 4; ++ss) {            // fixed order: identical in all slices
        offx += red[0 * 256 + ss * 64 + lane];
        offy += red[1 * 256 + ss * 64 + lane];
        z0   += red[2 * 256 + ss * 64 + lane];
        z1   += red[3 * 256 + ss * 64 + lane];
        z2   += red[4 * 256 + ss * 64 + lane];
        z3   += red[5 * 256 + ss * 64 + lane];
    }
    const float rg0 = 1.0f / (1.0f + __expf(-z0));
    const float rg1 = 1.0f / (1.0f + __expf(-z1));
    const float rg2 = 1.0f / (1.0f + __expf(-z2));
    const float rg3 = 1.0f / (1.0f + __expf(-z3));
    __syncthreads();                            // red reads done before comp writes

    // ===== phase 5: sampling-2 (per-pixel offsets, fp32 gathers) + compress =====
    float f[SC];
    float cp[8];
    #pragma unroll
    for (int d = 0; d < 8; ++d) cp[d] = 0.0f;
    {
        int j00, j10, j01, j11;
        float v00, v10, v01, v11;
        bilin_setup(gx + offx * (2.0f / (WIN - 1)),
                    gy + offy * (2.0f / (HIN - 1)),
                    j00, j10, j01, j11, v00, v10, v01, v11);
        #pragma unroll
        for (int kk = 0; kk < SC; kk += 4) {
            float l[16];
            #pragma unroll
            for (int k = 0; k < 4; ++k) {
                const float* __restrict__ xc = xb + (cb + kk + k) * HW;
                l[4*k+0] = xc[j00]; l[4*k+1] = xc[j10];
                l[4*k+2] = xc[j01]; l[4*k+3] = xc[j11];
            }
            #pragma unroll
            for (int k = 0; k < 4; ++k) {
                const float fc = l[4*k]*v00 + l[4*k+1]*v10 + l[4*k+2]*v01 + l[4*k+3]*v11;
                f[kk + k] = fc;
                const int c = cb + kk + k;
                const float s0 = rg0 * fc, s1 = rg1 * fc, s2 = rg2 * fc, s3 = rg3 * fc;
                #pragma unroll
                for (int d = 0; d < 8; ++d) {
                    cp[d] = fmaf(wcm[(0 * 8 + d) * C + c], s0, cp[d]);
                    cp[d] = fmaf(wcm[(1 * 8 + d) * C + c], s1, cp[d]);
                    cp[d] = fmaf(wcm[(2 * 8 + d) * C + c], s2, cp[d]);
                    cp[d] = fmaf(wcm[(3 * 8 + d) * C + c], s3, cp[d]);
                }
            }
        }
    }
    #pragma unroll
    for (int d = 0; d < 8; ++d) red[d * 256 + s * 64 + lane] = cp[d];
    __syncthreads();

    float comp[8];
    #pragma unroll
    for (int d = 0; d < 8; ++d) {
        float v = red[d * 256 + 0 * 64 + lane];
        v += red[d * 256 + 1 * 64 + lane];
        v += red[d * 256 + 2 * 64 + lane];
        v += red[d * 256 + 3 * 64 + lane];
        comp[d] = v;
    }

    // ===== phase 6: expand + residual for my 16 channels =====
    float* __restrict__ ob = out + bb * (C * OH * OW) + oy * OW + ox;
    #pragma unroll
    for (int k = 0; k < SC; ++k) {
        const int c = cb + k;
        const float* __restrict__ we0 = wex + (0 * C + c) * 8;
        const float* __restrict__ we1 = wex + (1 * C + c) * 8;
        const float* __restrict__ we2 = wex + (2 * C + c) * 8;
        const float* __restrict__ we3 = wex + (3 * C + c) * 8;
        float s0 = 0.0f, s1 = 0.0f, s2 = 0.0f, s3 = 0.0f;
        #pragma unroll
        for (int d = 0; d < 8; ++d) {
            s0 = fmaf(we0[d], comp[d], s0);
            s1 = fmaf(we1[d], comp[d], s1);
            s2 = fmaf(we2[d], comp[d], s2);
            s3 = fmaf(we3[d], comp[d], s3);
        }
        float acc2 = f[k];
        acc2 = fmaf(rg0, s0, acc2);
        acc2 = fmaf(rg1, s1, acc2);
        acc2 = fmaf(rg2, s2, acc2);
        acc2 = fmaf(rg3, s3, acc2);
        ob[c * (OH * OW)] = acc2;               // coalesced over 64 consecutive ox
    }
}

extern "C" void kernel_launch(void* const* d_in, const int* in_sizes, int n_in,
                              void* d_out, int out_size, void* d_ws, size_t ws_size,
                              hipStream_t stream) {
    const float* x   = (const float*)d_in[0];
    const float* wcm = (const float*)d_in[1];
    const float* wex = (const float*)d_in[2];
    const float* w1  = (const float*)d_in[3];
    const float* b1  = (const float*)d_in[4];
    const float* w2  = (const float*)d_in[5];
    const float* b2  = (const float*)d_in[6];
    const float* wr  = (const float*)d_in[7];
    const float* br  = (const float*)d_in[8];
    const float* wo  = (const float*)d_in[9];
    const float* bo  = (const float*)d_in[10];
    float* out = (float*)d_out;

    const int total  = BATCH * OH * OW;    // 131072 pixels
    const int blocks = total / PIX;        // 2048 blocks of 256 threads
    scab_kernel<<<blocks, BLK, 0, stream>>>(x, wcm, wex, w1, b1, w2, b2,
                                            wr, br, wo, bo, out);
}

// Round 8
// 119.305 us; speedup vs baseline: 1.5794x; 1.0466x over previous
//
#include <hip/hip_runtime.h>
#include <math.h>

// Fixed problem dims from setup_inputs()
#define BATCH 2
#define C 64
#define HIN 128
#define WIN 128
#define HW (HIN * WIN)
#define OH 256
#define OW 256

#define BLK 256
#define PIX 64    // pixels per block (64 consecutive ox in one oy row)
#define SC 16     // channels per thread-slice (4 slices)
#define ASTR 72   // act row stride in shorts (144 B rows, 16B aligned)
#define YSTR 36   // y row stride in floats (144 B, 16B aligned, 2-way banks)
#define OSTR 68   // ofs row stride in floats (272 B, 16B aligned)

// Round-8: compress/expand moved to MFMA as well. Round-7 evidence: wall
// 44us, VALU-issue ~25us, and ~1100 of ~1550 remaining VALU instrs/thread
// are the compress/expand FMA loops. Restructured with the per-pixel gate
// hoisted out:
//   GEMM-1: y[pix][eo] = fea0 x wcm^T   (64x64 @ 64x32, bf16 MFMA)
//   per-pixel: comp[d] = sum_e rg_e y[e*8+d]; t[ed] = rg_e comp[d]
//   GEMM-2: expand[pix][c] = t x wexR^T (64x32 @ 32x64, bf16 MFMA)
// fea0 is kept fp32 in registers for the residual; expand output goes
// through LDS back to the per-thread [pixel=lane][my 16ch] layout so the
// final global store stays coalesced.
// LDS: act bf16 64x72 (pf -> h1 -> emb -> fea0 -> t, barrier-separated)
//      red fp32 64x68 (head partials -> y(stride 36) -> ofs(stride 68)).

typedef __attribute__((ext_vector_type(8))) short bf16x8;
typedef __attribute__((ext_vector_type(4))) float f32x4;

__device__ __forceinline__ unsigned short f2bf(float f) {
    unsigned u = __float_as_uint(f);
    u += 0x7FFFu + ((u >> 16) & 1u);          // round-to-nearest-even
    return (unsigned short)(u >> 16);
}
__device__ __forceinline__ float bf2f(unsigned short s) {
    return __uint_as_float(((unsigned)s) << 16);
}

__device__ __forceinline__ void bilin_setup(float gx, float gy,
    int& i00, int& i10, int& i01, int& i11,
    float& w00, float& w10, float& w01, float& w11)
{
    const float fx = ((gx + 1.0f) * WIN - 1.0f) * 0.5f;
    const float fy = ((gy + 1.0f) * HIN - 1.0f) * 0.5f;
    const float x0 = floorf(fx), y0 = floorf(fy);
    const float wx1 = fx - x0, wx0 = 1.0f - wx1;
    const float wy1 = fy - y0, wy0 = 1.0f - wy1;
    const float x1 = x0 + 1.0f, y1 = y0 + 1.0f;
    const bool vx0 = (x0 >= 0.0f) && (x0 <= (float)(WIN - 1));
    const bool vx1 = (x1 >= 0.0f) && (x1 <= (float)(WIN - 1));
    const bool vy0 = (y0 >= 0.0f) && (y0 <= (float)(HIN - 1));
    const bool vy1 = (y1 >= 0.0f) && (y1 <= (float)(HIN - 1));
    const int xi0 = (int)fminf(fmaxf(x0, 0.0f), (float)(WIN - 1));
    const int xi1 = (int)fminf(fmaxf(x1, 0.0f), (float)(WIN - 1));
    const int yi0 = (int)fminf(fmaxf(y0, 0.0f), (float)(HIN - 1));
    const int yi1 = (int)fminf(fmaxf(y1, 0.0f), (float)(HIN - 1));
    w00 = wx0 * wy0 * ((vx0 && vy0) ? 1.0f : 0.0f);
    w10 = wx1 * wy0 * ((vx1 && vy0) ? 1.0f : 0.0f);
    w01 = wx0 * wy1 * ((vx0 && vy1) ? 1.0f : 0.0f);
    w11 = wx1 * wy1 * ((vx1 && vy1) ? 1.0f : 0.0f);
    i00 = yi0 * WIN + xi0;  i10 = yi0 * WIN + xi1;
    i01 = yi1 * WIN + xi0;  i11 = yi1 * WIN + xi1;
}

__global__ __launch_bounds__(BLK, 4) void scab_kernel(
    const float* __restrict__ x,    // (B, C, HIN, WIN)
    const float* __restrict__ wcm,  // weight_compress (4, 8, 64)
    const float* __restrict__ wex,  // weight_expand   (4, 64, 8)
    const float* __restrict__ w1,   // (64, 68)
    const float* __restrict__ b1,   // (64)
    const float* __restrict__ w2,   // (64, 64)
    const float* __restrict__ b2,   // (64)
    const float* __restrict__ wr,   // (4, 64)
    const float* __restrict__ br,   // (4)
    const float* __restrict__ wo,   // (2, 64)
    const float* __restrict__ bo,   // (2)
    float* __restrict__ out)        // (B, C, OH, OW)
{
    __shared__ __align__(16) short act[PIX * ASTR];   // 9216 B
    __shared__ __align__(16) float red[PIX * OSTR];   // 17408 B

    const int tid  = threadIdx.x;
    const int lane = tid & 63;                                  // pixel within block
    const int s    = __builtin_amdgcn_readfirstlane(tid >> 6);  // slice == wave id
    const int cb   = s * SC;
    const int l15  = lane & 15;
    const int quad = lane >> 4;
    const int nn   = cb + l15;                                  // my MFMA out-col

    const int gp = blockIdx.x * PIX + lane;
    const int ox = gp & (OW - 1);
    const int oy = (gp >> 8) & (OH - 1);
    const int bb = gp >> 16;

    // ---- base grid (fp32, matches reference) ----
    const float gx = ((ox + 0.5f) * 0.5f - 0.5f) * (2.0f / (WIN - 1)) - 1.0f;
    const float gy = ((oy + 0.5f) * 0.5f - 0.5f) * (2.0f / (HIN - 1)) - 1.0f;

    const float* __restrict__ xb = x + bb * (C * HW);

    // ===== B-frags from global (all rows k-contiguous) =====
    bf16x8 bw1[2], bw2[2], bwc[2], bwe;
    {
        const int nt1  = s & 1;                  // GEMM-1 n-tile of this wave
        const int eo_g = nt1 * 16 + l15;         // GEMM-1 out index (e*8+d)
        #pragma unroll
        for (int ks = 0; ks < 2; ++ks) {
            const float* __restrict__ s1p = w1 + nn * (C + 4) + 4 + ks * 32 + quad * 8;
            const float* __restrict__ s2p = w2 + nn * C + ks * 32 + quad * 8;
            const float* __restrict__ scp = wcm + eo_g * C + ks * 32 + quad * 8;
            #pragma unroll
            for (int j = 0; j < 8; ++j) {
                bw1[ks][j] = (short)f2bf(s1p[j]);
                bw2[ks][j] = (short)f2bf(s2p[j]);
                bwc[ks][j] = (short)f2bf(scp[j]);
            }
        }
        const float* __restrict__ sep = wex + (quad * C + nn) * 8;   // e=quad, d=j
        #pragma unroll
        for (int j = 0; j < 8; ++j) bwe[j] = (short)f2bf(sep[j]);
    }

    // ===== phase 1: sampling-1 gathers (my 16 ch), pf -> bf16 act[pix][ch] =====
    {
        int i00, i10, i01, i11;
        float w00, w10, w01, w11;
        bilin_setup(gx, gy, i00, i10, i01, i11, w00, w10, w01, w11);
        bf16x8 v0, v1;
        #pragma unroll
        for (int kk = 0; kk < SC; kk += 4) {
            float l[16];
            #pragma unroll
            for (int k = 0; k < 4; ++k) {
                const float* __restrict__ xc = xb + (cb + kk + k) * HW;
                l[4*k+0] = xc[i00]; l[4*k+1] = xc[i10];
                l[4*k+2] = xc[i01]; l[4*k+3] = xc[i11];
            }
            #pragma unroll
            for (int k = 0; k < 4; ++k) {
                const float pf = l[4*k]*w00 + l[4*k+1]*w10 + l[4*k+2]*w01 + l[4*k+3]*w11;
                const short b = (short)f2bf(pf);
                if (kk + k < 8) v0[kk + k] = b; else v1[kk + k - 8] = b;
            }
        }
        *(bf16x8*)&act[lane * ASTR + cb]     = v0;
        *(bf16x8*)&act[lane * ASTR + cb + 8] = v1;
    }
    __syncthreads();

    // ===== phase 2: conv1 via MFMA; coords+bias folded into C-init =====
    const float coor_h = (oy & 1) ? 0.25f : -0.25f;
    f32x4 acc[4];
    {
        const float4 wh = *(const float4*)(w1 + nn * (C + 4));   // w1[n][0..3]
        const float qn = b1[nn] + (wh.x + wh.y) * 0.5f + wh.z * coor_h;
        const float e0 = qn - 0.25f * wh.w;    // even pixel rows (reg 0,2)
        const float e1 = qn + 0.25f * wh.w;    // odd  pixel rows (reg 1,3)
        #pragma unroll
        for (int t = 0; t < 4; ++t) acc[t] = (f32x4){e0, e1, e0, e1};
    }
    #pragma unroll
    for (int t = 0; t < 4; ++t) {
        #pragma unroll
        for (int ks = 0; ks < 2; ++ks) {
            const bf16x8 af = *(const bf16x8*)&act[(t*16 + l15) * ASTR + ks*32 + quad*8];
            acc[t] = __builtin_amdgcn_mfma_f32_16x16x32_bf16(af, bw1[ks], acc[t], 0, 0, 0);
        }
    }
    __syncthreads();
    #pragma unroll
    for (int t = 0; t < 4; ++t)
        #pragma unroll
        for (int r = 0; r < 4; ++r)
            act[(t*16 + quad*4 + r) * ASTR + nn] = (short)f2bf(fmaxf(acc[t][r], 0.0f));
    __syncthreads();

    // ===== phase 3: conv2 via MFMA =====
    {
        const float b2n = b2[nn];
        #pragma unroll
        for (int t = 0; t < 4; ++t) acc[t] = (f32x4){b2n, b2n, b2n, b2n};
    }
    #pragma unroll
    for (int t = 0; t < 4; ++t) {
        #pragma unroll
        for (int ks = 0; ks < 2; ++ks) {
            const bf16x8 af = *(const bf16x8*)&act[(t*16 + l15) * ASTR + ks*32 + quad*8];
            acc[t] = __builtin_amdgcn_mfma_f32_16x16x32_bf16(af, bw2[ks], acc[t], 0, 0, 0);
        }
    }
    __syncthreads();
    #pragma unroll
    for (int t = 0; t < 4; ++t)
        #pragma unroll
        for (int r = 0; r < 4; ++r)
            act[(t*16 + quad*4 + r) * ASTR + nn] = (short)f2bf(fmaxf(acc[t][r], 0.0f));
    __syncthreads();

    // ===== phase 4: heads (pixel=lane, my 16 emb channels) + reduce =====
    float hx = 0.0f, hy = 0.0f, z0p = 0.0f, z1p = 0.0f, z2p = 0.0f, z3p = 0.0f;
    {
        const bf16x8 u0 = *(const bf16x8*)&act[lane * ASTR + cb];
        const bf16x8 u1 = *(const bf16x8*)&act[lane * ASTR + cb + 8];
        #pragma unroll
        for (int k = 0; k < SC; ++k) {
            const int o = cb + k;
            const float e = bf2f((unsigned short)(k < 8 ? u0[k] : u1[k - 8]));
            hx  = fmaf(wo[o],         e, hx);
            hy  = fmaf(wo[C + o],     e, hy);
            z0p = fmaf(wr[o],         e, z0p);
            z1p = fmaf(wr[C + o],     e, z1p);
            z2p = fmaf(wr[2 * C + o], e, z2p);
            z3p = fmaf(wr[3 * C + o], e, z3p);
        }
    }
    red[0 * 256 + s * 64 + lane] = hx;
    red[1 * 256 + s * 64 + lane] = hy;
    red[2 * 256 + s * 64 + lane] = z0p;
    red[3 * 256 + s * 64 + lane] = z1p;
    red[4 * 256 + s * 64 + lane] = z2p;
    red[5 * 256 + s * 64 + lane] = z3p;
    __syncthreads();

    float offx = bo[0], offy = bo[1];
    float z0 = br[0], z1 = br[1], z2 = br[2], z3 = br[3];
    #pragma unroll
    for (int ss = 0; ss < 4; ++ss) {            // fixed order: identical in all slices
        offx += red[0 * 256 + ss * 64 + lane];
        offy += red[1 * 256 + ss * 64 + lane];
        z0   += red[2 * 256 + ss * 64 + lane];
        z1   += red[3 * 256 + ss * 64 + lane];
        z2   += red[4 * 256 + ss * 64 + lane];
        z3   += red[5 * 256 + ss * 64 + lane];
    }
    const float rg0 = 1.0f / (1.0f + __expf(-z0));
    const float rg1 = 1.0f / (1.0f + __expf(-z1));
    const float rg2 = 1.0f / (1.0f + __expf(-z2));
    const float rg3 = 1.0f / (1.0f + __expf(-z3));

    // ===== phase 5: sampling-2 (per-pixel offsets); fea0 fp32 in regs + bf16 LDS =====
    float f[SC];
    {
        int j00, j10, j01, j11;
        float v00, v10, v01, v11;
        bilin_setup(gx + offx * (2.0f / (WIN - 1)),
                    gy + offy * (2.0f / (HIN - 1)),
                    j00, j10, j01, j11, v00, v10, v01, v11);
        bf16x8 v0, v1;
        #pragma unroll
        for (int kk = 0; kk < SC; kk += 4) {
            float l[16];
            #pragma unroll
            for (int k = 0; k < 4; ++k) {
                const float* __restrict__ xc = xb + (cb + kk + k) * HW;
                l[4*k+0] = xc[j00]; l[4*k+1] = xc[j10];
                l[4*k+2] = xc[j01]; l[4*k+3] = xc[j11];
            }
            #pragma unroll
            for (int k = 0; k < 4; ++k) {
                const float fc = l[4*k]*v00 + l[4*k+1]*v10 + l[4*k+2]*v01 + l[4*k+3]*v11;
                f[kk + k] = fc;
                const short b = (short)f2bf(fc);
                if (kk + k < 8) v0[kk + k] = b; else v1[kk + k - 8] = b;
            }
        }
        *(bf16x8*)&act[lane * ASTR + cb]     = v0;   // overwrite emb (post-B6)
        *(bf16x8*)&act[lane * ASTR + cb + 8] = v1;
    }
    __syncthreads();   // act(fea0) visible; head-partial reads of red all done

    // ===== phase 6: GEMM-1  y[pix][eo] = fea0 x wcm^T  (2 m-tiles/wave) =====
    {
        const int nt1 = s & 1;
        const int mb  = (s >> 1) * 2;
        #pragma unroll
        for (int mi = 0; mi < 2; ++mi) {
            const int mt = mb + mi;
            f32x4 yac = (f32x4){0.0f, 0.0f, 0.0f, 0.0f};
            #pragma unroll
            for (int ks = 0; ks < 2; ++ks) {
                const bf16x8 af = *(const bf16x8*)&act[(mt*16 + l15) * ASTR + ks*32 + quad*8];
                yac = __builtin_amdgcn_mfma_f32_16x16x32_bf16(af, bwc[ks], yac, 0, 0, 0);
            }
            #pragma unroll
            for (int r = 0; r < 4; ++r)
                red[(mt*16 + quad*4 + r) * YSTR + nt1*16 + l15] = yac[r];
        }
    }
    __syncthreads();

    // ===== phase 7: per-pixel gate fold: comp[d], t[ed] -> bf16 act[pix][0..31] =====
    {
        float comp[8];
        const float* __restrict__ yr = &red[lane * YSTR];
        #pragma unroll
        for (int d = 0; d < 8; ++d) {
            float v = rg0 * yr[d];
            v = fmaf(rg1, yr[8 + d],  v);
            v = fmaf(rg2, yr[16 + d], v);
            v = fmaf(rg3, yr[24 + d], v);
            comp[d] = v;
        }
        bf16x8 t0, t1, t2, t3;
        #pragma unroll
        for (int d = 0; d < 8; ++d) {
            t0[d] = (short)f2bf(rg0 * comp[d]);
            t1[d] = (short)f2bf(rg1 * comp[d]);
            t2[d] = (short)f2bf(rg2 * comp[d]);
            t3[d] = (short)f2bf(rg3 * comp[d]);
        }
        __syncthreads();   // all GEMM-1 act reads + y reads done
        *(bf16x8*)&act[lane * ASTR + 0]  = t0;
        *(bf16x8*)&act[lane * ASTR + 8]  = t1;
        *(bf16x8*)&act[lane * ASTR + 16] = t2;
        *(bf16x8*)&act[lane * ASTR + 24] = t3;
    }
    __syncthreads();

    // ===== phase 8: GEMM-2  expand[pix][c] = t x wexR^T  (4 m-tiles/wave) =====
    #pragma unroll
    for (int t = 0; t < 4; ++t) {
        f32x4 oac = (f32x4){0.0f, 0.0f, 0.0f, 0.0f};
        const bf16x8 af = *(const bf16x8*)&act[(t*16 + l15) * ASTR + quad*8];
        oac = __builtin_amdgcn_mfma_f32_16x16x32_bf16(af, bwe, oac, 0, 0, 0);
        #pragma unroll
        for (int r = 0; r < 4; ++r)
            red[(t*16 + quad*4 + r) * OSTR + nn] = oac[r];
    }
    __syncthreads();

    // ===== phase 9: residual + coalesced store (pixel=lane, my 16 ch) =====
    float* __restrict__ ob = out + bb * (C * OH * OW) + oy * OW + ox;
    const float* __restrict__ orow = &red[lane * OSTR + cb];
    #pragma unroll
    for (int kk = 0; kk < SC; kk += 4) {
        const float4 e4 = *(const float4*)(orow + kk);
        ob[(cb + kk + 0) * (OH * OW)] = f[kk + 0] + e4.x;
        ob[(cb + kk + 1) * (OH * OW)] = f[kk + 1] + e4.y;
        ob[(cb + kk + 2) * (OH * OW)] = f[kk + 2] + e4.z;
        ob[(cb + kk + 3) * (OH * OW)] = f[kk + 3] + e4.w;
    }
}

extern "C" void kernel_launch(void* const* d_in, const int* in_sizes, int n_in,
                              void* d_out, int out_size, void* d_ws, size_t ws_size,
                              hipStream_t stream) {
    const float* x   = (const float*)d_in[0];
    const float* wcm = (const float*)d_in[1];
    const float* wex = (const float*)d_in[2];
    const float* w1  = (const float*)d_in[3];
    const float* b1  = (const float*)d_in[4];
    const float* w2  = (const float*)d_in[5];
    const float* b2  = (const float*)d_in[6];
    const float* wr  = (const float*)d_in[7];
    const float* br  = (const float*)d_in[8];
    const float* wo  = (const float*)d_in[9];
    const float* bo  = (const float*)d_in[10];
    float* out = (float*)d_out;

    const int total  = BATCH * OH * OW;    // 131072 pixels
    const int blocks = total / PIX;        // 2048 blocks of 256 threads
    scab_kernel<<<blocks, BLK, 0, stream>>>(x, wcm, wex, w1, b1, w2, b2,
                                            wr, br, wo, bo, out);
}

// Round 9
// 117.994 us; speedup vs baseline: 1.5969x; 1.0111x over previous
//
#include <hip/hip_runtime.h>
#include <math.h>

// Fixed problem dims from setup_inputs()
#define BATCH 2
#define C 64
#define HIN 128
#define WIN 128
#define HW (HIN * WIN)
#define OH 256
#define OW 256

#define BLK 256
#define PIX 64    // pixels per block (64 consecutive ox in one oy row)
#define SC 16     // channels per thread-slice (4 slices)
#define ASTR 72   // act row stride in shorts (144 B rows, 16B aligned)
#define YHSTR 17  // y6 row stride in floats (odd -> conflict-free)
#define YSTR 33   // y32 row stride in floats (odd -> conflict-free)
#define OSTR 68   // ofs row stride in floats (272 B, 16B aligned)

// ws bf16 layout (shorts):
//  [    0.. 4095] w1k [n][64]   (w1[n][4+k])
//  [ 4096.. 8191] w2k [n][64]
//  [ 8192..10239] wcm [32][64]  (row eo=e*8+d, k-contig)
//  [10240..12287] wex [256][8]  (row e*64+c, k=d)
//  [12288..13311] whd [16][64]  (rows 0-1 wo, 2-5 wr, 6-15 zero)
#define WS_W2  4096
#define WS_WC  8192
#define WS_WE  10240
#define WS_WH  12288
#define WS_TOT 13312

// Round-9: (1) weights pre-packed to bf16 in d_ws by a tiny prep kernel --
// round-8 spent ~170 VALU + 56 divergent loads per thread re-converting
// weights in every block (2048x redundant). B-frags are now single
// dwordx4 loads. (2) heads moved to MFMA: [64pix x 64] x [64 x 6] GEMM,
// wave s does m-tile s with a zero-padded 16-row B-frag; y6 -> LDS
// (stride 17, conflict-free); all slices read identical values so the
// fp32 offsets/gates stay bitwise-identical across slices.

typedef __attribute__((ext_vector_type(8))) short bf16x8;
typedef __attribute__((ext_vector_type(4))) float f32x4;

__device__ __forceinline__ unsigned short f2bf(float f) {
    unsigned u = __float_as_uint(f);
    u += 0x7FFFu + ((u >> 16) & 1u);          // round-to-nearest-even
    return (unsigned short)(u >> 16);
}

__device__ __forceinline__ void bilin_setup(float gx, float gy,
    int& i00, int& i10, int& i01, int& i11,
    float& w00, float& w10, float& w01, float& w11)
{
    const float fx = ((gx + 1.0f) * WIN - 1.0f) * 0.5f;
    const float fy = ((gy + 1.0f) * HIN - 1.0f) * 0.5f;
    const float x0 = floorf(fx), y0 = floorf(fy);
    const float wx1 = fx - x0, wx0 = 1.0f - wx1;
    const float wy1 = fy - y0, wy0 = 1.0f - wy1;
    const float x1 = x0 + 1.0f, y1 = y0 + 1.0f;
    const bool vx0 = (x0 >= 0.0f) && (x0 <= (float)(WIN - 1));
    const bool vx1 = (x1 >= 0.0f) && (x1 <= (float)(WIN - 1));
    const bool vy0 = (y0 >= 0.0f) && (y0 <= (float)(HIN - 1));
    const bool vy1 = (y1 >= 0.0f) && (y1 <= (float)(HIN - 1));
    const int xi0 = (int)fminf(fmaxf(x0, 0.0f), (float)(WIN - 1));
    const int xi1 = (int)fminf(fmaxf(x1, 0.0f), (float)(WIN - 1));
    const int yi0 = (int)fminf(fmaxf(y0, 0.0f), (float)(HIN - 1));
    const int yi1 = (int)fminf(fmaxf(y1, 0.0f), (float)(HIN - 1));
    w00 = wx0 * wy0 * ((vx0 && vy0) ? 1.0f : 0.0f);
    w10 = wx1 * wy0 * ((vx1 && vy0) ? 1.0f : 0.0f);
    w01 = wx0 * wy1 * ((vx0 && vy1) ? 1.0f : 0.0f);
    w11 = wx1 * wy1 * ((vx1 && vy1) ? 1.0f : 0.0f);
    i00 = yi0 * WIN + xi0;  i10 = yi0 * WIN + xi1;
    i01 = yi1 * WIN + xi0;  i11 = yi1 * WIN + xi1;
}

__global__ __launch_bounds__(256) void prep_kernel(
    const float* __restrict__ wcm, const float* __restrict__ wex,
    const float* __restrict__ w1,  const float* __restrict__ w2,
    const float* __restrict__ wr,  const float* __restrict__ wo,
    unsigned short* __restrict__ wsb)
{
    const int i = blockIdx.x * 256 + threadIdx.x;
    if (i >= WS_TOT) return;
    float v = 0.0f;
    if (i < WS_W2) {                       // w1k
        const int n = i >> 6, k = i & 63;
        v = w1[n * (C + 4) + 4 + k];
    } else if (i < WS_WC) {                // w2k
        v = w2[i - WS_W2];
    } else if (i < WS_WE) {                // wcm
        v = wcm[i - WS_WC];
    } else if (i < WS_WH) {                // wex
        v = wex[i - WS_WE];
    } else {                               // whd (zero-padded to 16 rows)
        const int j = i - WS_WH;
        const int n = j >> 6, k = j & 63;
        v = (n < 2) ? wo[n * C + k] : ((n < 6) ? wr[(n - 2) * C + k] : 0.0f);
    }
    wsb[i] = f2bf(v);
}

__global__ __launch_bounds__(BLK, 4) void scab_kernel(
    const float* __restrict__ x,    // (B, C, HIN, WIN)
    const float* __restrict__ w1,   // (64, 68)  (coord cols + bias fold)
    const float* __restrict__ b1,   // (64)
    const float* __restrict__ b2,   // (64)
    const float* __restrict__ br,   // (4)
    const float* __restrict__ bo,   // (2)
    const unsigned short* __restrict__ wsb,  // pre-packed bf16 weights
    float* __restrict__ out)        // (B, C, OH, OW)
{
    __shared__ __align__(16) short act[PIX * ASTR];   // 9216 B
    __shared__ __align__(16) float red[PIX * OSTR];   // 17408 B

    const int tid  = threadIdx.x;
    const int lane = tid & 63;                                  // pixel within block
    const int s    = __builtin_amdgcn_readfirstlane(tid >> 6);  // slice == wave id
    const int cb   = s * SC;
    const int l15  = lane & 15;
    const int quad = lane >> 4;
    const int nn   = cb + l15;                                  // my MFMA out-col

    const int gp = blockIdx.x * PIX + lane;
    const int ox = gp & (OW - 1);
    const int oy = (gp >> 8) & (OH - 1);
    const int bb = gp >> 16;

    // ---- base grid (fp32, matches reference) ----
    const float gx = ((ox + 0.5f) * 0.5f - 0.5f) * (2.0f / (WIN - 1)) - 1.0f;
    const float gy = ((oy + 0.5f) * 0.5f - 0.5f) * (2.0f / (HIN - 1)) - 1.0f;

    const float* __restrict__ xb = x + bb * (C * HW);

    // ===== B-frags: single dwordx4 loads from pre-packed ws =====
    const int nt1  = s & 1;                  // GEMM-1 n-tile of this wave
    const int eo_g = nt1 * 16 + l15;         // GEMM-1 out index (e*8+d)
    bf16x8 bw1[2], bw2[2], bwc[2], bhd[2], bwe;
    #pragma unroll
    for (int ks = 0; ks < 2; ++ks) {
        bw1[ks] = *(const bf16x8*)(wsb +         nn   * 64 + ks * 32 + quad * 8);
        bw2[ks] = *(const bf16x8*)(wsb + WS_W2 + nn   * 64 + ks * 32 + quad * 8);
        bwc[ks] = *(const bf16x8*)(wsb + WS_WC + eo_g * 64 + ks * 32 + quad * 8);
        bhd[ks] = *(const bf16x8*)(wsb + WS_WH + l15  * 64 + ks * 32 + quad * 8);
    }
    bwe = *(const bf16x8*)(wsb + WS_WE + (quad * C + nn) * 8);

    // ===== phase 1: sampling-1 gathers (my 16 ch), pf -> bf16 act[pix][ch] =====
    {
        int i00, i10, i01, i11;
        float w00, w10, w01, w11;
        bilin_setup(gx, gy, i00, i10, i01, i11, w00, w10, w01, w11);
        bf16x8 v0, v1;
        #pragma unroll
        for (int kk = 0; kk < SC; kk += 4) {
            float l[16];
            #pragma unroll
            for (int k = 0; k < 4; ++k) {
                const float* __restrict__ xc = xb + (cb + kk + k) * HW;
                l[4*k+0] = xc[i00]; l[4*k+1] = xc[i10];
                l[4*k+2] = xc[i01]; l[4*k+3] = xc[i11];
            }
            #pragma unroll
            for (int k = 0; k < 4; ++k) {
                const float pf = l[4*k]*w00 + l[4*k+1]*w10 + l[4*k+2]*w01 + l[4*k+3]*w11;
                const short b = (short)f2bf(pf);
                if (kk + k < 8) v0[kk + k] = b; else v1[kk + k - 8] = b;
            }
        }
        *(bf16x8*)&act[lane * ASTR + cb]     = v0;
        *(bf16x8*)&act[lane * ASTR + cb + 8] = v1;
    }
    __syncthreads();

    // ===== phase 2: conv1 via MFMA; coords+bias folded into C-init =====
    const float coor_h = (oy & 1) ? 0.25f : -0.25f;
    f32x4 acc[4];
    {
        const float4 wh = *(const float4*)(w1 + nn * (C + 4));   // w1[n][0..3]
        const float qn = b1[nn] + (wh.x + wh.y) * 0.5f + wh.z * coor_h;
        const float e0 = qn - 0.25f * wh.w;    // even pixel rows (reg 0,2)
        const float e1 = qn + 0.25f * wh.w;    // odd  pixel rows (reg 1,3)
        #pragma unroll
        for (int t = 0; t < 4; ++t) acc[t] = (f32x4){e0, e1, e0, e1};
    }
    #pragma unroll
    for (int t = 0; t < 4; ++t) {
        #pragma unroll
        for (int ks = 0; ks < 2; ++ks) {
            const bf16x8 af = *(const bf16x8*)&act[(t*16 + l15) * ASTR + ks*32 + quad*8];
            acc[t] = __builtin_amdgcn_mfma_f32_16x16x32_bf16(af, bw1[ks], acc[t], 0, 0, 0);
        }
    }
    __syncthreads();
    #pragma unroll
    for (int t = 0; t < 4; ++t)
        #pragma unroll
        for (int r = 0; r < 4; ++r)
            act[(t*16 + quad*4 + r) * ASTR + nn] = (short)f2bf(fmaxf(acc[t][r], 0.0f));
    __syncthreads();

    // ===== phase 3: conv2 via MFMA =====
    {
        const float b2n = b2[nn];
        #pragma unroll
        for (int t = 0; t < 4; ++t) acc[t] = (f32x4){b2n, b2n, b2n, b2n};
    }
    #pragma unroll
    for (int t = 0; t < 4; ++t) {
        #pragma unroll
        for (int ks = 0; ks < 2; ++ks) {
            const bf16x8 af = *(const bf16x8*)&act[(t*16 + l15) * ASTR + ks*32 + quad*8];
            acc[t] = __builtin_amdgcn_mfma_f32_16x16x32_bf16(af, bw2[ks], acc[t], 0, 0, 0);
        }
    }
    __syncthreads();
    #pragma unroll
    for (int t = 0; t < 4; ++t)
        #pragma unroll
        for (int r = 0; r < 4; ++r)
            act[(t*16 + quad*4 + r) * ASTR + nn] = (short)f2bf(fmaxf(acc[t][r], 0.0f));
    __syncthreads();

    // ===== phase 4: heads via MFMA (wave s = m-tile s; n<6 used) =====
    {
        f32x4 yac = (f32x4){0.0f, 0.0f, 0.0f, 0.0f};
        #pragma unroll
        for (int ks = 0; ks < 2; ++ks) {
            const bf16x8 af = *(const bf16x8*)&act[(s*16 + l15) * ASTR + ks*32 + quad*8];
            yac = __builtin_amdgcn_mfma_f32_16x16x32_bf16(af, bhd[ks], yac, 0, 0, 0);
        }
        #pragma unroll
        for (int r = 0; r < 4; ++r)
            red[(s*16 + quad*4 + r) * YHSTR + l15] = yac[r];
    }
    __syncthreads();

    // ===== phase 5: offsets/gates from y6 (identical in all slices), then
    //        sampling-2 (per-pixel offsets); fea0 fp32 in regs + bf16 LDS =====
    const float* __restrict__ yp = &red[lane * YHSTR];
    const float offx = bo[0] + yp[0];
    const float offy = bo[1] + yp[1];
    const float rg0 = 1.0f / (1.0f + __expf(-(br[0] + yp[2])));
    const float rg1 = 1.0f / (1.0f + __expf(-(br[1] + yp[3])));
    const float rg2 = 1.0f / (1.0f + __expf(-(br[2] + yp[4])));
    const float rg3 = 1.0f / (1.0f + __expf(-(br[3] + yp[5])));

    float f[SC];
    {
        int j00, j10, j01, j11;
        float v00, v10, v01, v11;
        bilin_setup(gx + offx * (2.0f / (WIN - 1)),
                    gy + offy * (2.0f / (HIN - 1)),
                    j00, j10, j01, j11, v00, v10, v01, v11);
        bf16x8 v0, v1;
        #pragma unroll
        for (int kk = 0; kk < SC; kk += 4) {
            float l[16];
            #pragma unroll
            for (int k = 0; k < 4; ++k) {
                const float* __restrict__ xc = xb + (cb + kk + k) * HW;
                l[4*k+0] = xc[j00]; l[4*k+1] = xc[j10];
                l[4*k+2] = xc[j01]; l[4*k+3] = xc[j11];
            }
            #pragma unroll
            for (int k = 0; k < 4; ++k) {
                const float fc = l[4*k]*v00 + l[4*k+1]*v10 + l[4*k+2]*v01 + l[4*k+3]*v11;
                f[kk + k] = fc;
                const short b = (short)f2bf(fc);
                if (kk + k < 8) v0[kk + k] = b; else v1[kk + k - 8] = b;
            }
        }
        *(bf16x8*)&act[lane * ASTR + cb]     = v0;   // overwrite emb
        *(bf16x8*)&act[lane * ASTR + cb + 8] = v1;
    }
    __syncthreads();   // act(fea0) visible; all y6 reads done

    // ===== phase 6: GEMM-1  y[pix][eo] = fea0 x wcm^T  (2 m-tiles/wave) =====
    {
        const int mb = (s >> 1) * 2;
        #pragma unroll
        for (int mi = 0; mi < 2; ++mi) {
            const int mt = mb + mi;
            f32x4 yac = (f32x4){0.0f, 0.0f, 0.0f, 0.0f};
            #pragma unroll
            for (int ks = 0; ks < 2; ++ks) {
                const bf16x8 af = *(const bf16x8*)&act[(mt*16 + l15) * ASTR + ks*32 + quad*8];
                yac = __builtin_amdgcn_mfma_f32_16x16x32_bf16(af, bwc[ks], yac, 0, 0, 0);
            }
            #pragma unroll
            for (int r = 0; r < 4; ++r)
                red[(mt*16 + quad*4 + r) * YSTR + nt1*16 + l15] = yac[r];
        }
    }
    __syncthreads();

    // ===== phase 7: per-pixel gate fold: comp[d], t[ed] -> bf16 act[pix][0..31] =====
    {
        float comp[8];
        const float* __restrict__ yr = &red[lane * YSTR];
        #pragma unroll
        for (int d = 0; d < 8; ++d) {
            float v = rg0 * yr[d];
            v = fmaf(rg1, yr[8 + d],  v);
            v = fmaf(rg2, yr[16 + d], v);
            v = fmaf(rg3, yr[24 + d], v);
            comp[d] = v;
        }
        bf16x8 t0, t1;
        #pragma unroll
        for (int d = 0; d < 8; ++d) {
            t0[d] = (short)f2bf(rg0 * comp[d]);
            t1[d] = (short)f2bf(rg1 * comp[d]);
        }
        bf16x8 t2, t3;
        #pragma unroll
        for (int d = 0; d < 8; ++d) {
            t2[d] = (short)f2bf(rg2 * comp[d]);
            t3[d] = (short)f2bf(rg3 * comp[d]);
        }
        // GEMM-1's act reads completed before the last barrier; writing the
        // t-region is safe once this thread has read its y row. All y reads
        // happen before any act-t write below only within a thread, but
        // cross-wave: GEMM-1 readers of act finished pre-barrier; y readers
        // are this phase (red), t writes are act -- different arrays. Safe.
        *(bf16x8*)&act[lane * ASTR + 0]  = t0;
        *(bf16x8*)&act[lane * ASTR + 8]  = t1;
        *(bf16x8*)&act[lane * ASTR + 16] = t2;
        *(bf16x8*)&act[lane * ASTR + 24] = t3;
    }
    __syncthreads();

    // ===== phase 8: GEMM-2  expand[pix][c] = t x wexR^T  (4 m-tiles/wave) =====
    #pragma unroll
    for (int t = 0; t < 4; ++t) {
        f32x4 oac = (f32x4){0.0f, 0.0f, 0.0f, 0.0f};
        const bf16x8 af = *(const bf16x8*)&act[(t*16 + l15) * ASTR + quad*8];
        oac = __builtin_amdgcn_mfma_f32_16x16x32_bf16(af, bwe, oac, 0, 0, 0);
        #pragma unroll
        for (int r = 0; r < 4; ++r)
            red[(t*16 + quad*4 + r) * OSTR + nn] = oac[r];
    }
    __syncthreads();

    // ===== phase 9: residual + coalesced store (pixel=lane, my 16 ch) =====
    float* __restrict__ ob = out + bb * (C * OH * OW) + oy * OW + ox;
    const float* __restrict__ orow = &red[lane * OSTR + cb];
    #pragma unroll
    for (int kk = 0; kk < SC; kk += 4) {
        const float4 e4 = *(const float4*)(orow + kk);
        ob[(cb + kk + 0) * (OH * OW)] = f[kk + 0] + e4.x;
        ob[(cb + kk + 1) * (OH * OW)] = f[kk + 1] + e4.y;
        ob[(cb + kk + 2) * (OH * OW)] = f[kk + 2] + e4.z;
        ob[(cb + kk + 3) * (OH * OW)] = f[kk + 3] + e4.w;
    }
}

extern "C" void kernel_launch(void* const* d_in, const int* in_sizes, int n_in,
                              void* d_out, int out_size, void* d_ws, size_t ws_size,
                              hipStream_t stream) {
    const float* x   = (const float*)d_in[0];
    const float* wcm = (const float*)d_in[1];
    const float* wex = (const float*)d_in[2];
    const float* w1  = (const float*)d_in[3];
    const float* b1  = (const float*)d_in[4];
    const float* w2  = (const float*)d_in[5];
    const float* b2  = (const float*)d_in[6];
    const float* wr  = (const float*)d_in[7];
    const float* br  = (const float*)d_in[8];
    const float* wo  = (const float*)d_in[9];
    const float* bo  = (const float*)d_in[10];
    float* out = (float*)d_out;
    unsigned short* wsb = (unsigned short*)d_ws;

    // prep: pack weights to bf16 in ws (same work every call; stream-ordered)
    prep_kernel<<<(WS_TOT + 255) / 256, 256, 0, stream>>>(wcm, wex, w1, w2, wr, wo, wsb);

    const int total  = BATCH * OH * OW;    // 131072 pixels
    const int blocks = total / PIX;        // 2048 blocks of 256 threads
    scab_kernel<<<blocks, BLK, 0, stream>>>(x, w1, b1, b2, br, bo, wsb, out);
}